// Round 8
// baseline (169.544 us; speedup 1.0000x reference)
//
#include <hip/hip_runtime.h>

// ============================================================================
// r8: same verified semantics as r7 (directed pairs, rev-first interleave),
// optimized: i-atom hoisting across the 4-pair group (-40% VMEM loads) and
// non-temporal streaming stores (output is write-once, 469MB >> 32MB L2).
//   E = 2P = 33,538,048 directed pairs; layout idx0|idx1|dist|diff*3|valid.
//   d even: (j,i), diff=c[j]-c[i];  d odd: (i,j), diff=c[i]-c[j].
// ============================================================================

namespace r8 {

constexpr int kM = 8;
constexpr int kN = 2048;
constexpr int kPPM = kN * (kN - 1) / 2;     // 2,096,128 triu pairs per molecule
constexpr int kP   = kPPM * kM;             // 16,769,024 triu pairs total
constexpr long long E = 2LL * kP;           // 33,538,048 directed pairs

typedef __attribute__((ext_vector_type(8))) unsigned short u16x8;

__device__ __forceinline__ unsigned short f2bf(float f) {
    unsigned int u = __float_as_uint(f);
    u += 0x7FFFu + ((u >> 16) & 1u);        // round-to-nearest-even
    return (unsigned short)(u >> 16);
}

__device__ __forceinline__ int row_off(int i) {
    return (i * (2 * kN - 1 - i)) >> 1;
}

__global__ __launch_bounds__(256)
void fp_r8(const int* __restrict__ species,
           const float* __restrict__ coords,
           const int* __restrict__ cutw,
           unsigned short* __restrict__ out)
{
#pragma clang fp contract(off)
    const int g = blockIdx.x * 256 + threadIdx.x;   // group of 4 triu ranks
    const int t0 = g * 4;
    if (t0 >= kP) return;

    const int m = t0 / kPPM;                // 4 | kPPM -> group never crosses mol
    const int r0 = t0 - m * kPPM;

    // invert triangular index (4095^2 = 16,769,025 exact in f32)
    const float s = (float)(16769025 - 8 * r0);
    int i = (int)floorf((4095.0f - sqrtf(s)) * 0.5f);
    i = min(max(i, 0), kN - 2);
    while (row_off(i) > r0) --i;
    while (row_off(i + 1) <= r0) ++i;
    int j = i + 1 + (r0 - row_off(i));

    // cutoff: robust decode (int32 / int64-low-word / float32)
    const int w0 = cutw[0];
    const float cutoff = (w0 > 0 && w0 < (1 << 20)) ? (float)w0 : __int_as_float(w0);

    const int base = m * kN;

    // hoisted i-atom state (reloaded only on row wrap, ~0.4% of iterations)
    int a = base + i;
    float ax = coords[3 * a + 0], ay = coords[3 * a + 1], az = coords[3 * a + 2];
    int   sa = species[a];
    unsigned short ba = f2bf((float)a);

    u16x8 vi0, vi1, vd, vv;
    u16x8 vf0, vf1, vf2;
    unsigned short df[24];

#pragma unroll
    for (int k = 0; k < 4; ++k) {
        const int b = base + j;

        const float bx = coords[3 * b + 0], by = coords[3 * b + 1], bz = coords[3 * b + 2];
        const int   sb = species[b];

        const float dx = ax - bx;
        const float dy = ay - by;
        const float dz = az - bz;
        const float d2 = dx * dx + dy * dy + dz * dz;   // no FMA: match np exactly
        const float dist = sqrtf(d2);

        const bool dummy = (sa == -1) || (sb == -1);
        const bool valid = (dist <= cutoff) && !dummy;

        const unsigned short bb = f2bf((float)b);
        const unsigned short bd = valid ? f2bf(dist) : (unsigned short)0;
        const unsigned short bv = valid ? (unsigned short)0x3F80 : (unsigned short)0;
        const unsigned short fx = valid ? f2bf(dx) : (unsigned short)0;   // fwd (i,j)
        const unsigned short fy = valid ? f2bf(dy) : (unsigned short)0;
        const unsigned short fz = valid ? f2bf(dz) : (unsigned short)0;
        const unsigned short gx = valid ? (unsigned short)(fx ^ 0x8000) : (unsigned short)0;
        const unsigned short gy = valid ? (unsigned short)(fy ^ 0x8000) : (unsigned short)0;
        const unsigned short gz = valid ? (unsigned short)(fz ^ 0x8000) : (unsigned short)0;

        // REV first (slot 2k): (j,i), diff = -(fwd); FWD second (slot 2k+1)
        vi0[2 * k]     = bb;  vi0[2 * k + 1] = ba;
        vi1[2 * k]     = ba;  vi1[2 * k + 1] = bb;
        vd[2 * k]      = bd;  vd[2 * k + 1]  = bd;
        vv[2 * k]      = bv;  vv[2 * k + 1]  = bv;
        df[6 * k + 0] = gx;  df[6 * k + 1] = gy;  df[6 * k + 2] = gz;
        df[6 * k + 3] = fx;  df[6 * k + 4] = fy;  df[6 * k + 5] = fz;

        // advance to next triu rank; reload hoisted i-state on row wrap
        ++j;
        if (j == kN) {
            ++i; j = i + 1;
            if (k < 3) {
                a = base + i;
                ax = coords[3 * a + 0]; ay = coords[3 * a + 1]; az = coords[3 * a + 2];
                sa = species[a];
                ba = f2bf((float)a);
            }
        }
    }

#pragma unroll
    for (int e = 0; e < 8; ++e) {
        vf0[e] = df[e];
        vf1[e] = df[8 + e];
        vf2[e] = df[16 + e];
    }

    // 16B-aligned non-temporal vector stores (full 64B line coverage per wave)
    __builtin_nontemporal_store(vi0, (u16x8*)(out) + g);           // idx0
    __builtin_nontemporal_store(vi1, (u16x8*)(out + E) + g);       // idx1
    __builtin_nontemporal_store(vd,  (u16x8*)(out + 2 * E) + g);   // dist
    u16x8* dfp = (u16x8*)(out + 3 * E) + 3 * g;                    // diff
    __builtin_nontemporal_store(vf0, dfp + 0);
    __builtin_nontemporal_store(vf1, dfp + 1);
    __builtin_nontemporal_store(vf2, dfp + 2);
    __builtin_nontemporal_store(vv,  (u16x8*)(out + 6 * E) + g);   // valid
}

} // namespace r8

extern "C" void kernel_launch(void* const* d_in, const int* in_sizes, int n_in,
                              void* d_out, int out_size, void* d_ws, size_t ws_size,
                              hipStream_t stream) {
    using namespace r8;
    const int*   species = (const int*)d_in[0];
    const float* coords  = (const float*)d_in[1];
    const int*   cutoff  = (const int*)d_in[2];
    unsigned short* out  = (unsigned short*)d_out;

    const int groups = kP / 4;                   // 4,192,256
    const int blocks = groups / 256;             // 16,376 exact
    fp_r8<<<blocks, 256, 0, stream>>>(species, coords, cutoff, out);
}

// Round 9
// 82.487 us; speedup vs baseline: 2.0554x; 2.0554x over previous
//
#include <hip/hip_runtime.h>

// ============================================================================
// r9: r7 semantics (verified) + i-atom hoisting; NT stores REVERTED (r8 post-
// mortem: __builtin_nontemporal_store cost +76% — nt bypasses L2 allocate and
// defeats the write-combine drain path; plain stores ride the ~6.9TB/s path).
//   E = 2P = 33,538,048 directed pairs; layout idx0|idx1|dist|diff*3|valid.
//   d even: (j,i), diff=c[j]-c[i];  d odd: (i,j), diff=c[i]-c[j].
// ============================================================================

namespace r9 {

constexpr int kM = 8;
constexpr int kN = 2048;
constexpr int kPPM = kN * (kN - 1) / 2;     // 2,096,128 triu pairs per molecule
constexpr int kP   = kPPM * kM;             // 16,769,024 triu pairs total
constexpr long long E = 2LL * kP;           // 33,538,048 directed pairs

typedef __attribute__((ext_vector_type(8))) unsigned short u16x8;

__device__ __forceinline__ unsigned short f2bf(float f) {
    unsigned int u = __float_as_uint(f);
    u += 0x7FFFu + ((u >> 16) & 1u);        // round-to-nearest-even
    return (unsigned short)(u >> 16);
}

__device__ __forceinline__ int row_off(int i) {
    return (i * (2 * kN - 1 - i)) >> 1;
}

__global__ __launch_bounds__(256)
void fp_r9(const int* __restrict__ species,
           const float* __restrict__ coords,
           const int* __restrict__ cutw,
           unsigned short* __restrict__ out)
{
#pragma clang fp contract(off)
    const int g = blockIdx.x * 256 + threadIdx.x;   // group of 4 triu ranks
    const int t0 = g * 4;
    if (t0 >= kP) return;

    const int m = t0 / kPPM;                // 4 | kPPM -> group never crosses mol
    const int r0 = t0 - m * kPPM;

    // invert triangular index (4095^2 = 16,769,025 exact in f32)
    const float s = (float)(16769025 - 8 * r0);
    int i = (int)floorf((4095.0f - sqrtf(s)) * 0.5f);
    i = min(max(i, 0), kN - 2);
    while (row_off(i) > r0) --i;
    while (row_off(i + 1) <= r0) ++i;
    int j = i + 1 + (r0 - row_off(i));

    // cutoff: robust decode (int32 / int64-low-word / float32)
    const int w0 = cutw[0];
    const float cutoff = (w0 > 0 && w0 < (1 << 20)) ? (float)w0 : __int_as_float(w0);

    const int base = m * kN;

    // hoisted i-atom state (reloaded only on row wrap, ~0.4% of iterations)
    int a = base + i;
    float ax = coords[3 * a + 0], ay = coords[3 * a + 1], az = coords[3 * a + 2];
    int   sa = species[a];
    unsigned short ba = f2bf((float)a);

    u16x8 vi0, vi1, vd, vv;
    u16x8 vf0, vf1, vf2;
    unsigned short df[24];

#pragma unroll
    for (int k = 0; k < 4; ++k) {
        const int b = base + j;

        const float bx = coords[3 * b + 0], by = coords[3 * b + 1], bz = coords[3 * b + 2];
        const int   sb = species[b];

        const float dx = ax - bx;
        const float dy = ay - by;
        const float dz = az - bz;
        const float d2 = dx * dx + dy * dy + dz * dz;   // no FMA: match np exactly
        const float dist = sqrtf(d2);

        const bool dummy = (sa == -1) || (sb == -1);
        const bool valid = (dist <= cutoff) && !dummy;

        const unsigned short bb = f2bf((float)b);
        const unsigned short bd = valid ? f2bf(dist) : (unsigned short)0;
        const unsigned short bv = valid ? (unsigned short)0x3F80 : (unsigned short)0;
        const unsigned short fx = valid ? f2bf(dx) : (unsigned short)0;   // fwd (i,j)
        const unsigned short fy = valid ? f2bf(dy) : (unsigned short)0;
        const unsigned short fz = valid ? f2bf(dz) : (unsigned short)0;
        const unsigned short gx = valid ? (unsigned short)(fx ^ 0x8000) : (unsigned short)0;
        const unsigned short gy = valid ? (unsigned short)(fy ^ 0x8000) : (unsigned short)0;
        const unsigned short gz = valid ? (unsigned short)(fz ^ 0x8000) : (unsigned short)0;

        // REV first (slot 2k): (j,i), diff = -(fwd); FWD second (slot 2k+1)
        vi0[2 * k]     = bb;  vi0[2 * k + 1] = ba;
        vi1[2 * k]     = ba;  vi1[2 * k + 1] = bb;
        vd[2 * k]      = bd;  vd[2 * k + 1]  = bd;
        vv[2 * k]      = bv;  vv[2 * k + 1]  = bv;
        df[6 * k + 0] = gx;  df[6 * k + 1] = gy;  df[6 * k + 2] = gz;
        df[6 * k + 3] = fx;  df[6 * k + 4] = fy;  df[6 * k + 5] = fz;

        // advance to next triu rank; reload hoisted i-state on row wrap
        ++j;
        if (j == kN) {
            ++i; j = i + 1;
            if (k < 3) {
                a = base + i;
                ax = coords[3 * a + 0]; ay = coords[3 * a + 1]; az = coords[3 * a + 2];
                sa = species[a];
                ba = f2bf((float)a);
            }
        }
    }

#pragma unroll
    for (int e = 0; e < 8; ++e) {
        vf0[e] = df[e];
        vf1[e] = df[8 + e];
        vf2[e] = df[16 + e];
    }

    // 16B-aligned PLAIN vector stores (L2 write-combine path)
    *((u16x8*)(out) + g)             = vi0;   // idx0
    *((u16x8*)(out + E) + g)         = vi1;   // idx1
    *((u16x8*)(out + 2 * E) + g)     = vd;    // dist
    u16x8* dfp = (u16x8*)(out + 3 * E) + 3 * g;   // diff
    dfp[0] = vf0; dfp[1] = vf1; dfp[2] = vf2;
    *((u16x8*)(out + 6 * E) + g)     = vv;    // valid
}

} // namespace r9

extern "C" void kernel_launch(void* const* d_in, const int* in_sizes, int n_in,
                              void* d_out, int out_size, void* d_ws, size_t ws_size,
                              hipStream_t stream) {
    using namespace r9;
    const int*   species = (const int*)d_in[0];
    const float* coords  = (const float*)d_in[1];
    const int*   cutoff  = (const int*)d_in[2];
    unsigned short* out  = (unsigned short*)d_out;

    const int groups = kP / 4;                   // 4,192,256
    const int blocks = groups / 256;             // 16,376 exact
    fp_r9<<<blocks, 256, 0, stream>>>(species, coords, cutoff, out);
}